// Round 7
// baseline (491.556 us; speedup 1.0000x reference)
//
#include <hip/hip_runtime.h>
#include <hip/hip_bf16.h>
#include <math.h>

#define B_ 4
#define N_ 8192
#define K_ 16
#define BN_ (B_ * N_)
#define EPS_ 1e-5f

#define S_ 8              // candidate splits = waves per block (knn)
#define TPB (S_ * 64)     // 512 threads (knn)
#define QPB 64            // queries per block (knn)
#define MCAND (N_ / S_)   // candidates per wave (knn)
#define DEPTH 16          // deferred-insert buffer depth per lane (knn)

#define NBLK 512          // persistent tail blocks (2/CU, co-resident via launch_bounds(256,2))
#define ROWS 64           // rows per tail block (4 threads/row)

// ---------------- pack coords (B*N,3) -> float4 ----------------
__global__ __launch_bounds__(256) void pack_coords(const float* __restrict__ coords,
                                                   float4* __restrict__ out) {
    int i = blockIdx.x * 256 + threadIdx.x;
    if (i >= BN_) return;
    out[i] = make_float4(coords[3 * i], coords[3 * i + 1], coords[3 * i + 2], 0.0f);
}

// ---------------- exact 16-NN (unchanged from round 5) ----------------
__global__ __launch_bounds__(512) void knn_kernel(const float4* __restrict__ coords4,
                                                  int* __restrict__ idxOut) {
    __shared__ float2 bufp[DEPTH][TPB];       // 64 KB
    __shared__ float thr2d[S_][64];           // 2 KB shared thresholds

    const int bpb = N_ / QPB;                 // 128 blocks per batch
    int b = blockIdx.x / bpb;
    int qbase = (blockIdx.x % bpb) * QPB;
    int t = threadIdx.x;
    int lane = t & 63;
    int w = __builtin_amdgcn_readfirstlane(t >> 6);
    int q = qbase + lane;

    thr2d[t >> 6][lane] = 3.4e38f;
    __syncthreads();

    const float4* cb = coords4 + (size_t)b * N_;
    float4 qc = cb[q];
    float qx = qc.x, qy = qc.y, qz = qc.z;

    float key[K_];
    int   id[K_];
#pragma unroll
    for (int j = 0; j < K_; j++) { key[j] = 3.4e38f; id[j] = -1; }

    int cnt = 0;
    float bound = 3.4e38f;
    float lim = 3.4e38f;

    auto flush = [&]() {
        for (int j = 0; j < cnt; ++j) {
            float2 e = bufp[j][t];
            float d2 = e.x;
            int   m  = __float_as_int(e.y);
            if (d2 < key[K_ - 1]) {
#pragma unroll
                for (int jj = K_ - 1; jj > 0; --jj) {
                    bool up = d2 < key[jj - 1];
                    float ik = fminf(d2, key[jj]);
                    int   ii = (d2 < key[jj]) ? m : id[jj];
                    key[jj] = up ? key[jj - 1] : ik;
                    id[jj]  = up ? id[jj - 1]  : ii;
                }
                if (d2 < key[0]) { key[0] = d2; id[0] = m; }
            }
        }
        cnt = 0;
    };

    auto proc = [&](float4 c, int m) {
        float dx = qx - c.x, dy = qy - c.y, dz = qz - c.z;
        float d2 = dx * dx;
        d2 = fmaf(dy, dy, d2);
        d2 = fmaf(dz, dz, d2);
        if (d2 < lim) {
            bufp[cnt][t] = make_float2(d2, __int_as_float(m));
            cnt++;
        }
    };

    const int base = w * MCAND;
    for (int i = 0; i < MCAND; i += 8) {
        float4 c0 = cb[base + i + 0];
        float4 c1 = cb[base + i + 1];
        float4 c2 = cb[base + i + 2];
        float4 c3 = cb[base + i + 3];
        float4 c4 = cb[base + i + 4];
        float4 c5 = cb[base + i + 5];
        float4 c6 = cb[base + i + 6];
        float4 c7 = cb[base + i + 7];
        proc(c0, base + i + 0);
        proc(c1, base + i + 1);
        proc(c2, base + i + 2);
        proc(c3, base + i + 3);
        proc(c4, base + i + 4);
        proc(c5, base + i + 5);
        proc(c6, base + i + 6);
        proc(c7, base + i + 7);
        if (__any(cnt >= DEPTH - 7)) {
            flush();
            lim = fminf(key[K_ - 1], bound);
        }
        if ((i & 56) == 56) {
            thr2d[w][lane] = key[K_ - 1];
            float m0 = fminf(thr2d[0][lane], thr2d[1][lane]);
            float m1 = fminf(thr2d[2][lane], thr2d[3][lane]);
            float m2 = fminf(thr2d[4][lane], thr2d[5][lane]);
            float m3 = fminf(thr2d[6][lane], thr2d[7][lane]);
            bound = fminf(fminf(m0, m1), fminf(m2, m3));
            lim = fminf(key[K_ - 1], bound);
        }
    }
    flush();

#pragma unroll
    for (int j = 0; j < K_; j++) bufp[j][t] = make_float2(key[j], __int_as_float(id[j]));

    int* op = idxOut + ((size_t)b * N_ + q) * K_;
    for (int step = 1; step < S_; step <<= 1) {
        bool active = (w & (2 * step - 1)) == 0;
        float md[K_];
        int   mi[K_];
        __syncthreads();
        if (active) {
            int pa = t, pb = t + step * 64;
            int ia = 0, ib = 0;
#pragma unroll
            for (int r = 0; r < K_; ++r) {
                float2 ea = bufp[ia][pa];
                float2 eb = bufp[ib][pb];
                bool sel = ea.x <= eb.x;
                md[r] = sel ? ea.x : eb.x;
                mi[r] = __float_as_int(sel ? ea.y : eb.y);
                ia += sel ? 1 : 0;
                ib += sel ? 0 : 1;
            }
        }
        __syncthreads();
        if (active) {
            if (step == S_ / 2) {
#pragma unroll
                for (int r = 0; r < K_; ++r) op[r] = mi[r];
            } else {
#pragma unroll
                for (int r = 0; r < K_; ++r) bufp[r][t] = make_float2(md[r], __int_as_float(mi[r]));
            }
        }
    }
}

// ---------------- device-scope grid barrier (persistent kernel) ----------------
// counter zeroed each launch via hipMemsetAsync; monotone targets -> no reset race.
__device__ __forceinline__ void gridbar(int* cnt, int target) {
    __syncthreads();
    if (threadIdx.x == 0) {
        __threadfence();
        atomicAdd(cnt, 1);
        while (__hip_atomic_load(cnt, __ATOMIC_RELAXED, __HIP_MEMORY_SCOPE_AGENT) < target)
            __builtin_amdgcn_s_sleep(2);
        __threadfence();
    }
    __syncthreads();
}

// ---------------- persistent fused tail v2: spill-free, scalar-broadcast weights ----------------
// 512 blocks x 256 threads, 2 blocks/CU. 4 threads/row (h2 = t>>6, wave-uniform),
// 64 rows/block. Weights read via wave-uniform addresses -> s_load broadcast
// (no LDS staging). Row exchange via +1-padded LDS (conflict-free). Per-thread
// arrays: x[64] + acc[16]/acc32[32] -> ~116 VGPR, no spill.
__global__ __launch_bounds__(256, 2) void fused_tail(
        const float* __restrict__ feats, const int* __restrict__ idx,
        const float* __restrict__ W1, const float* __restrict__ b1,
        const float* __restrict__ g1, const float* __restrict__ be1,
        const float* __restrict__ Wa, const float* __restrict__ ba,
        const float* __restrict__ ga, const float* __restrict__ bea,
        const float* __restrict__ W2, const float* __restrict__ b2,
        const float* __restrict__ g2, const float* __restrict__ be2,
        float* __restrict__ out,
        float* __restrict__ part1, float* __restrict__ part2, float* __restrict__ part3,
        int* __restrict__ barcnt) {
    __shared__ float buf[ROWS][65];    // 16.6 KB, +1 pad -> conflict-free
    __shared__ float red[256];
    __shared__ float scs[128], shs[128];

    int t = threadIdx.x;
    int rl = t & 63;                                   // row within block = lane
    int h2 = __builtin_amdgcn_readfirstlane(t >> 6);   // quarter id, wave-uniform
    int row = blockIdx.x * ROWS + rl;
    int bb = row >> 13;

    const float* fb = feats + ((size_t)bb << 13) * 64;
    const int* ip = idx + (size_t)row * K_;

    // ---- gather + mean: this thread's 16 channels [h2*16, h2*16+16)
    float xh[16];
#pragma unroll
    for (int j = 0; j < 16; j++) xh[j] = 0.0f;
#pragma unroll
    for (int j = 0; j < K_; j++) {
        const float4* np = (const float4*)(fb + (size_t)ip[j] * 64 + h2 * 16);
#pragma unroll
        for (int f = 0; f < 4; f++) {
            float4 v = np[f];
            xh[4 * f] += v.x; xh[4 * f + 1] += v.y; xh[4 * f + 2] += v.z; xh[4 * f + 3] += v.w;
        }
    }
#pragma unroll
    for (int j = 0; j < 16; j++) xh[j] *= (1.0f / 16.0f);

    // ---- stage x0, assemble full row
#pragma unroll
    for (int j = 0; j < 16; j++) buf[rl][h2 * 16 + j] = xh[j];
    __syncthreads();
    float x[64];
#pragma unroll
    for (int c = 0; c < 64; c++) x[c] = buf[rl][c];

    // ---- mm1: 16 outputs, weights via s_load broadcast
    float acc[16];
#pragma unroll
    for (int j = 0; j < 16; j++) acc[j] = b1[h2 * 16 + j];
#pragma unroll
    for (int c = 0; c < 64; c++) {
        float xv = x[c];
        const float* wr = W1 + c * 64 + h2 * 16;
#pragma unroll
        for (int j = 0; j < 16; j++) acc[j] = fmaf(xv, wr[j], acc[j]);
    }

    // ---- stage y1, stats partials
    __syncthreads();
#pragma unroll
    for (int j = 0; j < 16; j++) buf[rl][h2 * 16 + j] = acc[j];
    __syncthreads();
    if (t < 128) {
        int c = t & 63;
        float s = 0.0f;
        if (t < 64) { for (int r = 0; r < ROWS; ++r) s += buf[r][c]; }
        else        { for (int r = 0; r < ROWS; ++r) { float v = buf[r][c]; s = fmaf(v, v, s); } }
        part1[blockIdx.x * 128 + t] = s;
    }
    gridbar(barcnt, NBLK);

    if (t < 128) {
        float s = 0.0f;
#pragma unroll 8
        for (int g = 0; g < NBLK; ++g) s += part1[g * 128 + t];
        red[t] = s;
    }
    __syncthreads();
    if (t < 64) {
        float mean = red[t] * (1.0f / BN_);
        float var = red[t + 64] * (1.0f / BN_) - mean * mean;
        float rstd = rsqrtf(var + EPS_);
        float scl = rstd * g1[t];
        scs[t] = scl;
        shs[t] = be1[t] - mean * scl;
    }
    __syncthreads();

    // ---- x1 = relu(bn1(y1)); stage full x1
#pragma unroll
    for (int j = 0; j < 16; j++)
        acc[j] = fmaxf(0.0f, fmaf(acc[j], scs[h2 * 16 + j], shs[h2 * 16 + j]));
#pragma unroll
    for (int j = 0; j < 16; j++) buf[rl][h2 * 16 + j] = acc[j];
    __syncthreads();
#pragma unroll
    for (int c = 0; c < 64; c++) x[c] = buf[rl][c];

    // ---- mm2: y2 = x1 @ Wa + ba
#pragma unroll
    for (int j = 0; j < 16; j++) acc[j] = ba[h2 * 16 + j];
#pragma unroll
    for (int c = 0; c < 64; c++) {
        float xv = x[c];
        const float* wr = Wa + c * 64 + h2 * 16;
#pragma unroll
        for (int j = 0; j < 16; j++) acc[j] = fmaf(xv, wr[j], acc[j]);
    }

    // ---- stage y2, stats partials
    __syncthreads();
#pragma unroll
    for (int j = 0; j < 16; j++) buf[rl][h2 * 16 + j] = acc[j];
    __syncthreads();
    if (t < 128) {
        int c = t & 63;
        float s = 0.0f;
        if (t < 64) { for (int r = 0; r < ROWS; ++r) s += buf[r][c]; }
        else        { for (int r = 0; r < ROWS; ++r) { float v = buf[r][c]; s = fmaf(v, v, s); } }
        part2[blockIdx.x * 128 + t] = s;
    }
    gridbar(barcnt, 2 * NBLK);

    if (t < 128) {
        float s = 0.0f;
#pragma unroll 8
        for (int g = 0; g < NBLK; ++g) s += part2[g * 128 + t];
        red[t] = s;
    }
    __syncthreads();
    if (t < 64) {
        float mean = red[t] * (1.0f / BN_);
        float var = red[t + 64] * (1.0f / BN_) - mean * mean;
        float rstd = rsqrtf(var + EPS_);
        float scl = rstd * ga[t];
        scs[t] = scl;
        shs[t] = bea[t] - mean * scl;
    }
    __syncthreads();

    // ---- fx = x1 * (1 + sigmoid(relu(bn2(y2)))); stage full fx
#pragma unroll
    for (int j = 0; j < 16; j++) {
        float tv = fmaxf(0.0f, fmaf(acc[j], scs[h2 * 16 + j], shs[h2 * 16 + j]));
        float a = 1.0f / (1.0f + __expf(-tv));
        acc[j] = x[h2 * 16 + j] * (1.0f + a);
    }
#pragma unroll
    for (int j = 0; j < 16; j++) buf[rl][h2 * 16 + j] = acc[j];
    __syncthreads();
#pragma unroll
    for (int c = 0; c < 64; c++) x[c] = buf[rl][c];

    // ---- mm3: 32 outputs per thread [h2*32, h2*32+32)
    float acc32[32];
#pragma unroll
    for (int j = 0; j < 32; j++) acc32[j] = b2[h2 * 32 + j];
#pragma unroll
    for (int c = 0; c < 64; c++) {
        float xv = x[c];
        const float* wr = W2 + c * 128 + h2 * 32;
#pragma unroll
        for (int j = 0; j < 32; j++) acc32[j] = fmaf(xv, wr[j], acc32[j]);
    }
    float4* op = (float4*)(out + (size_t)row * 128 + h2 * 32);
#pragma unroll
    for (int f = 0; f < 8; f++)
        op[f] = make_float4(acc32[4 * f], acc32[4 * f + 1], acc32[4 * f + 2], acc32[4 * f + 3]);

    // ---- y3 stats: round 0 (channels 0-63 from h2<2), round 1 (64-127 from h2>=2)
    __syncthreads();
    if (h2 < 2) {
#pragma unroll
        for (int j = 0; j < 32; j++) buf[rl][h2 * 32 + j] = acc32[j];
    }
    __syncthreads();
    if (t < 128) {
        int c = t & 63;
        float s = 0.0f;
        if (t < 64) { for (int r = 0; r < ROWS; ++r) s += buf[r][c]; }
        else        { for (int r = 0; r < ROWS; ++r) { float v = buf[r][c]; s = fmaf(v, v, s); } }
        part3[blockIdx.x * 256 + t] = s;
    }
    __syncthreads();
    if (h2 >= 2) {
#pragma unroll
        for (int j = 0; j < 32; j++) buf[rl][(h2 - 2) * 32 + j] = acc32[j];
    }
    __syncthreads();
    if (t < 128) {
        int c = t & 63;
        float s = 0.0f;
        if (t < 64) { for (int r = 0; r < ROWS; ++r) s += buf[r][c]; }
        else        { for (int r = 0; r < ROWS; ++r) { float v = buf[r][c]; s = fmaf(v, v, s); } }
        part3[blockIdx.x * 256 + 128 + t] = s;
    }
    gridbar(barcnt, 3 * NBLK);

    {
        float s = 0.0f;
#pragma unroll 8
        for (int g = 0; g < NBLK; ++g) s += part3[g * 256 + t];
        red[t] = s;
    }
    __syncthreads();
    if (t < 128) {
        int c = t;
        int si = (c < 64) ? c : (c + 64);     // sum slot; sumsq at si+64
        float mean = red[si] * (1.0f / BN_);
        float var = red[si + 64] * (1.0f / BN_) - mean * mean;
        float rstd = rsqrtf(var + EPS_);
        float scl = rstd * g2[c];
        scs[c] = scl;
        shs[c] = be2[c] - mean * scl;
    }
    __syncthreads();

    // ---- final: normalize own 32 channels in-place (L2-hot)
#pragma unroll
    for (int f = 0; f < 8; f++) {
        float4 v = op[f];
        int c0 = h2 * 32 + 4 * f;
        v.x = fmaxf(0.0f, fmaf(v.x, scs[c0],     shs[c0]));
        v.y = fmaxf(0.0f, fmaf(v.y, scs[c0 + 1], shs[c0 + 1]));
        v.z = fmaxf(0.0f, fmaf(v.z, scs[c0 + 2], shs[c0 + 2]));
        v.w = fmaxf(0.0f, fmaf(v.w, scs[c0 + 3], shs[c0 + 3]));
        op[f] = v;
    }
}

extern "C" void kernel_launch(void* const* d_in, const int* in_sizes, int n_in,
                              void* d_out, int out_size, void* d_ws, size_t ws_size,
                              hipStream_t stream) {
    const float* coords = (const float*)d_in[0];
    const float* feats  = (const float*)d_in[1];
    const float* W1  = (const float*)d_in[3];
    const float* b1  = (const float*)d_in[4];
    const float* g1  = (const float*)d_in[5];
    const float* be1 = (const float*)d_in[6];
    const float* Wa  = (const float*)d_in[7];
    const float* ba  = (const float*)d_in[8];
    const float* ga  = (const float*)d_in[9];
    const float* bea = (const float*)d_in[10];
    const float* W2  = (const float*)d_in[11];
    const float* b2  = (const float*)d_in[12];
    const float* g2  = (const float*)d_in[13];
    const float* be2 = (const float*)d_in[14];

    float* ws = (float*)d_ws;
    float4* coords4 = (float4*)ws;                         // 131072 floats
    int*    idxbuf  = (int*)(ws + 131072);                 // BN_*16 ints
    float*  part1 = ws + 131072 + 524288;                  // NBLK*128
    float*  part2 = part1 + NBLK * 128;                    // NBLK*128
    float*  part3 = part2 + NBLK * 128;                    // NBLK*256
    int*    barcnt = (int*)(part3 + NBLK * 256);
    float*  y3 = (float*)d_out;

    hipMemsetAsync(barcnt, 0, 64, stream);
    pack_coords<<<(BN_ + 255) / 256, 256, 0, stream>>>(coords, coords4);
    knn_kernel<<<B_ * (N_ / QPB), TPB, 0, stream>>>(coords4, idxbuf);

    fused_tail<<<NBLK, 256, 0, stream>>>(feats, idxbuf,
                                         W1, b1, g1, be1,
                                         Wa, ba, ga, bea,
                                         W2, b2, g2, be2,
                                         y3, part1, part2, part3, barcnt);
}

// Round 8
// 458.701 us; speedup vs baseline: 1.0716x; 1.0716x over previous
//
#include <hip/hip_runtime.h>
#include <hip/hip_bf16.h>
#include <math.h>

#define B_ 4
#define N_ 8192
#define K_ 16
#define BN_ (B_ * N_)
#define EPS_ 1e-5f

#define S_ 8              // candidate splits = waves per block (knn)
#define TPB (S_ * 64)     // 512 threads (knn)
#define QPB 64            // queries per block (knn)
#define MCAND (N_ / S_)   // candidates per wave (knn)
#define DEPTH 16          // deferred-insert buffer depth per lane (knn)

#define NBLK 512          // persistent tail blocks (2/CU co-resident)
#define ROWS 64           // rows per tail block (4 threads/row)

// ---------------- pack coords (B*N,3) -> float4 ----------------
__global__ __launch_bounds__(256) void pack_coords(const float* __restrict__ coords,
                                                   float4* __restrict__ out) {
    int i = blockIdx.x * 256 + threadIdx.x;
    if (i >= BN_) return;
    out[i] = make_float4(coords[3 * i], coords[3 * i + 1], coords[3 * i + 2], 0.0f);
}

// ---------------- exact 16-NN (unchanged from round 5) ----------------
__global__ __launch_bounds__(512) void knn_kernel(const float4* __restrict__ coords4,
                                                  int* __restrict__ idxOut) {
    __shared__ float2 bufp[DEPTH][TPB];       // 64 KB
    __shared__ float thr2d[S_][64];           // 2 KB shared thresholds

    const int bpb = N_ / QPB;                 // 128 blocks per batch
    int b = blockIdx.x / bpb;
    int qbase = (blockIdx.x % bpb) * QPB;
    int t = threadIdx.x;
    int lane = t & 63;
    int w = __builtin_amdgcn_readfirstlane(t >> 6);
    int q = qbase + lane;

    thr2d[t >> 6][lane] = 3.4e38f;
    __syncthreads();

    const float4* cb = coords4 + (size_t)b * N_;
    float4 qc = cb[q];
    float qx = qc.x, qy = qc.y, qz = qc.z;

    float key[K_];
    int   id[K_];
#pragma unroll
    for (int j = 0; j < K_; j++) { key[j] = 3.4e38f; id[j] = -1; }

    int cnt = 0;
    float bound = 3.4e38f;
    float lim = 3.4e38f;

    auto flush = [&]() {
        for (int j = 0; j < cnt; ++j) {
            float2 e = bufp[j][t];
            float d2 = e.x;
            int   m  = __float_as_int(e.y);
            if (d2 < key[K_ - 1]) {
#pragma unroll
                for (int jj = K_ - 1; jj > 0; --jj) {
                    bool up = d2 < key[jj - 1];
                    float ik = fminf(d2, key[jj]);
                    int   ii = (d2 < key[jj]) ? m : id[jj];
                    key[jj] = up ? key[jj - 1] : ik;
                    id[jj]  = up ? id[jj - 1]  : ii;
                }
                if (d2 < key[0]) { key[0] = d2; id[0] = m; }
            }
        }
        cnt = 0;
    };

    auto proc = [&](float4 c, int m) {
        float dx = qx - c.x, dy = qy - c.y, dz = qz - c.z;
        float d2 = dx * dx;
        d2 = fmaf(dy, dy, d2);
        d2 = fmaf(dz, dz, d2);
        if (d2 < lim) {
            bufp[cnt][t] = make_float2(d2, __int_as_float(m));
            cnt++;
        }
    };

    const int base = w * MCAND;
    for (int i = 0; i < MCAND; i += 8) {
        float4 c0 = cb[base + i + 0];
        float4 c1 = cb[base + i + 1];
        float4 c2 = cb[base + i + 2];
        float4 c3 = cb[base + i + 3];
        float4 c4 = cb[base + i + 4];
        float4 c5 = cb[base + i + 5];
        float4 c6 = cb[base + i + 6];
        float4 c7 = cb[base + i + 7];
        proc(c0, base + i + 0);
        proc(c1, base + i + 1);
        proc(c2, base + i + 2);
        proc(c3, base + i + 3);
        proc(c4, base + i + 4);
        proc(c5, base + i + 5);
        proc(c6, base + i + 6);
        proc(c7, base + i + 7);
        if (__any(cnt >= DEPTH - 7)) {
            flush();
            lim = fminf(key[K_ - 1], bound);
        }
        if ((i & 56) == 56) {
            thr2d[w][lane] = key[K_ - 1];
            float m0 = fminf(thr2d[0][lane], thr2d[1][lane]);
            float m1 = fminf(thr2d[2][lane], thr2d[3][lane]);
            float m2 = fminf(thr2d[4][lane], thr2d[5][lane]);
            float m3 = fminf(thr2d[6][lane], thr2d[7][lane]);
            bound = fminf(fminf(m0, m1), fminf(m2, m3));
            lim = fminf(key[K_ - 1], bound);
        }
    }
    flush();

#pragma unroll
    for (int j = 0; j < K_; j++) bufp[j][t] = make_float2(key[j], __int_as_float(id[j]));

    int* op = idxOut + ((size_t)b * N_ + q) * K_;
    for (int step = 1; step < S_; step <<= 1) {
        bool active = (w & (2 * step - 1)) == 0;
        float md[K_];
        int   mi[K_];
        __syncthreads();
        if (active) {
            int pa = t, pb = t + step * 64;
            int ia = 0, ib = 0;
#pragma unroll
            for (int r = 0; r < K_; ++r) {
                float2 ea = bufp[ia][pa];
                float2 eb = bufp[ib][pb];
                bool sel = ea.x <= eb.x;
                md[r] = sel ? ea.x : eb.x;
                mi[r] = __float_as_int(sel ? ea.y : eb.y);
                ia += sel ? 1 : 0;
                ib += sel ? 0 : 1;
            }
        }
        __syncthreads();
        if (active) {
            if (step == S_ / 2) {
#pragma unroll
                for (int r = 0; r < K_; ++r) op[r] = mi[r];
            } else {
#pragma unroll
                for (int r = 0; r < K_; ++r) bufp[r][t] = make_float2(md[r], __int_as_float(mi[r]));
            }
        }
    }
}

// ---------------- device-scope grid barrier (persistent kernel) ----------------
__device__ __forceinline__ void gridbar(int* cnt, int target) {
    __syncthreads();
    if (threadIdx.x == 0) {
        __threadfence();
        atomicAdd(cnt, 1);
        while (__hip_atomic_load(cnt, __ATOMIC_RELAXED, __HIP_MEMORY_SCOPE_AGENT) < target)
            __builtin_amdgcn_s_sleep(2);
        __threadfence();
    }
    __syncthreads();
}

// ---------------- persistent fused tail v3: chunked LDS reads, tiny register footprint ----------------
// 512 blocks x 256 threads (2/CU). 4 threads/row, 64 rows/block. Row data lives in
// +1-padded LDS; mm loops read x in 16-float chunks (unroll 1 on chunk loop keeps
// live ranges small: acc[16]+xr[16]+x1s[16] ~ 60 VGPR -> no scratch). Weights via
// wave-uniform s_load broadcast. Output written ONCE, post-normalization.
__global__ __launch_bounds__(256, 2) void fused_tail(
        const float* __restrict__ feats, const int* __restrict__ idx,
        const float* __restrict__ W1, const float* __restrict__ b1,
        const float* __restrict__ g1, const float* __restrict__ be1,
        const float* __restrict__ Wa, const float* __restrict__ ba,
        const float* __restrict__ ga, const float* __restrict__ bea,
        const float* __restrict__ W2, const float* __restrict__ b2,
        const float* __restrict__ g2, const float* __restrict__ be2,
        float* __restrict__ out,
        float* __restrict__ part1, float* __restrict__ part2, float* __restrict__ part3,
        int* __restrict__ barcnt) {
    __shared__ float buf[ROWS][65];    // 16.6 KB, odd stride -> conflict-free
    __shared__ float red[256];
    __shared__ float scs[128], shs[128];

    int t = threadIdx.x;
    int rl = t & 63;                                   // row within block
    int h2 = __builtin_amdgcn_readfirstlane(t >> 6);   // quarter id (wave-uniform)
    int row = blockIdx.x * ROWS + rl;
    int bb = row >> 13;

    const float* fb = feats + ((size_t)bb << 13) * 64;
    const int* ip = idx + (size_t)row * K_;

    // ---- gather + mean: this thread's 16 channels, stage to LDS
    {
        float xh[16];
#pragma unroll
        for (int j = 0; j < 16; j++) xh[j] = 0.0f;
#pragma unroll
        for (int j = 0; j < K_; j++) {
            const float4* np = (const float4*)(fb + (size_t)ip[j] * 64 + h2 * 16);
#pragma unroll
            for (int f = 0; f < 4; f++) {
                float4 v = np[f];
                xh[4 * f] += v.x; xh[4 * f + 1] += v.y; xh[4 * f + 2] += v.z; xh[4 * f + 3] += v.w;
            }
        }
#pragma unroll
        for (int j = 0; j < 16; j++) buf[rl][h2 * 16 + j] = xh[j] * (1.0f / 16.0f);
    }
    __syncthreads();

    // ---- mm1: 16 outputs; x read in 16-chunks from LDS; weights via s_load
    float acc[16];
#pragma unroll
    for (int j = 0; j < 16; j++) acc[j] = b1[h2 * 16 + j];
#pragma unroll 1
    for (int c0 = 0; c0 < 64; c0 += 16) {
        float xr[16];
#pragma unroll
        for (int j = 0; j < 16; j++) xr[j] = buf[rl][c0 + j];
#pragma unroll
        for (int cc = 0; cc < 16; cc++) {
            float xv = xr[cc];
            const float* wr = W1 + (c0 + cc) * 64 + h2 * 16;
#pragma unroll
            for (int j = 0; j < 16; j++) acc[j] = fmaf(xv, wr[j], acc[j]);
        }
    }

    // ---- stage y1, stats partials
    __syncthreads();
#pragma unroll
    for (int j = 0; j < 16; j++) buf[rl][h2 * 16 + j] = acc[j];
    __syncthreads();
    if (t < 128) {
        int c = t & 63;
        float s = 0.0f;
        if (t < 64) { for (int r = 0; r < ROWS; ++r) s += buf[r][c]; }
        else        { for (int r = 0; r < ROWS; ++r) { float v = buf[r][c]; s = fmaf(v, v, s); } }
        part1[blockIdx.x * 128 + t] = s;
    }
    gridbar(barcnt, NBLK);

    if (t < 128) {
        float s = 0.0f;
#pragma unroll 8
        for (int g = 0; g < NBLK; ++g) s += part1[g * 128 + t];
        red[t] = s;
    }
    __syncthreads();
    if (t < 64) {
        float mean = red[t] * (1.0f / BN_);
        float var = red[t + 64] * (1.0f / BN_) - mean * mean;
        float rstd = rsqrtf(var + EPS_);
        float scl = rstd * g1[t];
        scs[t] = scl;
        shs[t] = be1[t] - mean * scl;
    }
    __syncthreads();

    // ---- x1 = relu(bn1(y1)); keep own slice in x1s; stage full x1
    float x1s[16];
#pragma unroll
    for (int j = 0; j < 16; j++) {
        x1s[j] = fmaxf(0.0f, fmaf(acc[j], scs[h2 * 16 + j], shs[h2 * 16 + j]));
        buf[rl][h2 * 16 + j] = x1s[j];
    }
    __syncthreads();

    // ---- mm2: y2 = x1 @ Wa + ba
#pragma unroll
    for (int j = 0; j < 16; j++) acc[j] = ba[h2 * 16 + j];
#pragma unroll 1
    for (int c0 = 0; c0 < 64; c0 += 16) {
        float xr[16];
#pragma unroll
        for (int j = 0; j < 16; j++) xr[j] = buf[rl][c0 + j];
#pragma unroll
        for (int cc = 0; cc < 16; cc++) {
            float xv = xr[cc];
            const float* wr = Wa + (c0 + cc) * 64 + h2 * 16;
#pragma unroll
            for (int j = 0; j < 16; j++) acc[j] = fmaf(xv, wr[j], acc[j]);
        }
    }

    // ---- stage y2, stats partials
    __syncthreads();
#pragma unroll
    for (int j = 0; j < 16; j++) buf[rl][h2 * 16 + j] = acc[j];
    __syncthreads();
    if (t < 128) {
        int c = t & 63;
        float s = 0.0f;
        if (t < 64) { for (int r = 0; r < ROWS; ++r) s += buf[r][c]; }
        else        { for (int r = 0; r < ROWS; ++r) { float v = buf[r][c]; s = fmaf(v, v, s); } }
        part2[blockIdx.x * 128 + t] = s;
    }
    gridbar(barcnt, 2 * NBLK);

    if (t < 128) {
        float s = 0.0f;
#pragma unroll 8
        for (int g = 0; g < NBLK; ++g) s += part2[g * 128 + t];
        red[t] = s;
    }
    __syncthreads();
    if (t < 64) {
        float mean = red[t] * (1.0f / BN_);
        float var = red[t + 64] * (1.0f / BN_) - mean * mean;
        float rstd = rsqrtf(var + EPS_);
        float scl = rstd * ga[t];
        scs[t] = scl;
        shs[t] = bea[t] - mean * scl;
    }
    __syncthreads();

    // ---- fx = x1 * (1 + sigmoid(relu(bn2(y2)))); stage full fx
#pragma unroll
    for (int j = 0; j < 16; j++) {
        float tv = fmaxf(0.0f, fmaf(acc[j], scs[h2 * 16 + j], shs[h2 * 16 + j]));
        float a = 1.0f / (1.0f + __expf(-tv));
        buf[rl][h2 * 16 + j] = x1s[j] * (1.0f + a);
    }
    __syncthreads();

    // ---- mm3: 32 outputs per thread [h2*32, h2*32+32)
    float acc32[32];
#pragma unroll
    for (int j = 0; j < 32; j++) acc32[j] = b2[h2 * 32 + j];
#pragma unroll 1
    for (int c0 = 0; c0 < 64; c0 += 16) {
        float xr[16];
#pragma unroll
        for (int j = 0; j < 16; j++) xr[j] = buf[rl][c0 + j];
#pragma unroll
        for (int cc = 0; cc < 16; cc++) {
            float xv = xr[cc];
            const float* wr = W2 + (c0 + cc) * 128 + h2 * 32;
#pragma unroll
            for (int j = 0; j < 32; j++) acc32[j] = fmaf(xv, wr[j], acc32[j]);
        }
    }

    // ---- y3 stats: round 0 (ch 0-63 from h2<2), round 1 (ch 64-127 from h2>=2)
    __syncthreads();
    if (h2 < 2) {
#pragma unroll
        for (int j = 0; j < 32; j++) buf[rl][h2 * 32 + j] = acc32[j];
    }
    __syncthreads();
    if (t < 128) {
        int c = t & 63;
        float s = 0.0f;
        if (t < 64) { for (int r = 0; r < ROWS; ++r) s += buf[r][c]; }
        else        { for (int r = 0; r < ROWS; ++r) { float v = buf[r][c]; s = fmaf(v, v, s); } }
        part3[blockIdx.x * 256 + t] = s;
    }
    __syncthreads();
    if (h2 >= 2) {
#pragma unroll
        for (int j = 0; j < 32; j++) buf[rl][(h2 - 2) * 32 + j] = acc32[j];
    }
    __syncthreads();
    if (t < 128) {
        int c = t & 63;
        float s = 0.0f;
        if (t < 64) { for (int r = 0; r < ROWS; ++r) s += buf[r][c]; }
        else        { for (int r = 0; r < ROWS; ++r) { float v = buf[r][c]; s = fmaf(v, v, s); } }
        part3[blockIdx.x * 256 + 128 + t] = s;
    }
    gridbar(barcnt, 3 * NBLK);

    {
        float s = 0.0f;
#pragma unroll 8
        for (int g = 0; g < NBLK; ++g) s += part3[g * 256 + t];
        red[t] = s;
    }
    __syncthreads();
    if (t < 128) {
        int c = t;
        int si = (c < 64) ? c : (c + 64);     // sum slot; sumsq at si+64
        float mean = red[si] * (1.0f / BN_);
        float var = red[si + 64] * (1.0f / BN_) - mean * mean;
        float rstd = rsqrtf(var + EPS_);
        float scl = rstd * g2[c];
        scs[c] = scl;
        shs[c] = be2[c] - mean * scl;
    }
    __syncthreads();

    // ---- final: normalize in registers, single output write
    float4* op = (float4*)(out + (size_t)row * 128 + h2 * 32);
#pragma unroll
    for (int f = 0; f < 8; f++) {
        int c0 = h2 * 32 + 4 * f;
        float4 v;
        v.x = fmaxf(0.0f, fmaf(acc32[4 * f],     scs[c0],     shs[c0]));
        v.y = fmaxf(0.0f, fmaf(acc32[4 * f + 1], scs[c0 + 1], shs[c0 + 1]));
        v.z = fmaxf(0.0f, fmaf(acc32[4 * f + 2], scs[c0 + 2], shs[c0 + 2]));
        v.w = fmaxf(0.0f, fmaf(acc32[4 * f + 3], scs[c0 + 3], shs[c0 + 3]));
        op[f] = v;
    }
}

extern "C" void kernel_launch(void* const* d_in, const int* in_sizes, int n_in,
                              void* d_out, int out_size, void* d_ws, size_t ws_size,
                              hipStream_t stream) {
    const float* coords = (const float*)d_in[0];
    const float* feats  = (const float*)d_in[1];
    const float* W1  = (const float*)d_in[3];
    const float* b1  = (const float*)d_in[4];
    const float* g1  = (const float*)d_in[5];
    const float* be1 = (const float*)d_in[6];
    const float* Wa  = (const float*)d_in[7];
    const float* ba  = (const float*)d_in[8];
    const float* ga  = (const float*)d_in[9];
    const float* bea = (const float*)d_in[10];
    const float* W2  = (const float*)d_in[11];
    const float* b2  = (const float*)d_in[12];
    const float* g2  = (const float*)d_in[13];
    const float* be2 = (const float*)d_in[14];

    float* ws = (float*)d_ws;
    float4* coords4 = (float4*)ws;                         // 131072 floats
    int*    idxbuf  = (int*)(ws + 131072);                 // BN_*16 ints
    float*  part1 = ws + 131072 + 524288;                  // NBLK*128
    float*  part2 = part1 + NBLK * 128;                    // NBLK*128
    float*  part3 = part2 + NBLK * 128;                    // NBLK*256
    int*    barcnt = (int*)(part3 + NBLK * 256);
    float*  y3 = (float*)d_out;

    hipMemsetAsync(barcnt, 0, 64, stream);
    pack_coords<<<(BN_ + 255) / 256, 256, 0, stream>>>(coords, coords4);
    knn_kernel<<<B_ * (N_ / QPB), TPB, 0, stream>>>(coords4, idxbuf);

    fused_tail<<<NBLK, 256, 0, stream>>>(feats, idxbuf,
                                         W1, b1, g1, be1,
                                         Wa, ba, ga, bea,
                                         W2, b2, g2, be2,
                                         y3, part1, part2, part3, barcnt);
}

// Round 9
// 427.576 us; speedup vs baseline: 1.1496x; 1.0728x over previous
//
#include <hip/hip_runtime.h>
#include <hip/hip_bf16.h>
#include <hip/hip_fp16.h>
#include <math.h>

#define B_ 4
#define N_ 8192
#define K_ 16
#define BN_ (B_ * N_)
#define EPS_ 1e-5f

#define S_ 8              // candidate splits = waves per block (knn)
#define TPB (S_ * 64)     // 512 threads (knn)
#define QPB 64            // queries per block (knn)
#define MCAND (N_ / S_)   // candidates per wave (knn)
#define DEPTH 16          // deferred-insert buffer depth per lane (knn)

#define NBLK 512          // persistent tail blocks (2/CU co-resident)
#define ROWS 64           // rows per tail block (8 threads/row)

// ---------------- pack coords (B*N,3) -> float4 ----------------
__global__ __launch_bounds__(256) void pack_coords(const float* __restrict__ coords,
                                                   float4* __restrict__ out) {
    int i = blockIdx.x * 256 + threadIdx.x;
    if (i >= BN_) return;
    out[i] = make_float4(coords[3 * i], coords[3 * i + 1], coords[3 * i + 2], 0.0f);
}

// ---------------- feats fp32 -> fp16 (halves gather footprint AND traffic) ----------------
__global__ __launch_bounds__(256) void feats2h(const float* __restrict__ in,
                                               __half* __restrict__ outh) {
    int i = blockIdx.x * 256 + threadIdx.x;       // one thread per 8 elements
    const float4* p = (const float4*)(in + (size_t)i * 8);
    float4 a = p[0], b = p[1];
    __half2 h0; h0.x = __float2half_rn(a.x); h0.y = __float2half_rn(a.y);
    __half2 h1; h1.x = __float2half_rn(a.z); h1.y = __float2half_rn(a.w);
    __half2 h2; h2.x = __float2half_rn(b.x); h2.y = __float2half_rn(b.y);
    __half2 h3; h3.x = __float2half_rn(b.z); h3.y = __float2half_rn(b.w);
    uint4 o;
    o.x = *(unsigned*)&h0; o.y = *(unsigned*)&h1; o.z = *(unsigned*)&h2; o.w = *(unsigned*)&h3;
    ((uint4*)outh)[i] = o;
}

// ---------------- exact 16-NN (unchanged from round 5) ----------------
__global__ __launch_bounds__(512) void knn_kernel(const float4* __restrict__ coords4,
                                                  int* __restrict__ idxOut) {
    __shared__ float2 bufp[DEPTH][TPB];       // 64 KB
    __shared__ float thr2d[S_][64];           // 2 KB shared thresholds

    const int bpb = N_ / QPB;                 // 128 blocks per batch
    int b = blockIdx.x / bpb;
    int qbase = (blockIdx.x % bpb) * QPB;
    int t = threadIdx.x;
    int lane = t & 63;
    int w = __builtin_amdgcn_readfirstlane(t >> 6);
    int q = qbase + lane;

    thr2d[t >> 6][lane] = 3.4e38f;
    __syncthreads();

    const float4* cb = coords4 + (size_t)b * N_;
    float4 qc = cb[q];
    float qx = qc.x, qy = qc.y, qz = qc.z;

    float key[K_];
    int   id[K_];
#pragma unroll
    for (int j = 0; j < K_; j++) { key[j] = 3.4e38f; id[j] = -1; }

    int cnt = 0;
    float bound = 3.4e38f;
    float lim = 3.4e38f;

    auto flush = [&]() {
        for (int j = 0; j < cnt; ++j) {
            float2 e = bufp[j][t];
            float d2 = e.x;
            int   m  = __float_as_int(e.y);
            if (d2 < key[K_ - 1]) {
#pragma unroll
                for (int jj = K_ - 1; jj > 0; --jj) {
                    bool up = d2 < key[jj - 1];
                    float ik = fminf(d2, key[jj]);
                    int   ii = (d2 < key[jj]) ? m : id[jj];
                    key[jj] = up ? key[jj - 1] : ik;
                    id[jj]  = up ? id[jj - 1]  : ii;
                }
                if (d2 < key[0]) { key[0] = d2; id[0] = m; }
            }
        }
        cnt = 0;
    };

    auto proc = [&](float4 c, int m) {
        float dx = qx - c.x, dy = qy - c.y, dz = qz - c.z;
        float d2 = dx * dx;
        d2 = fmaf(dy, dy, d2);
        d2 = fmaf(dz, dz, d2);
        if (d2 < lim) {
            bufp[cnt][t] = make_float2(d2, __int_as_float(m));
            cnt++;
        }
    };

    const int base = w * MCAND;
    for (int i = 0; i < MCAND; i += 8) {
        float4 c0 = cb[base + i + 0];
        float4 c1 = cb[base + i + 1];
        float4 c2 = cb[base + i + 2];
        float4 c3 = cb[base + i + 3];
        float4 c4 = cb[base + i + 4];
        float4 c5 = cb[base + i + 5];
        float4 c6 = cb[base + i + 6];
        float4 c7 = cb[base + i + 7];
        proc(c0, base + i + 0);
        proc(c1, base + i + 1);
        proc(c2, base + i + 2);
        proc(c3, base + i + 3);
        proc(c4, base + i + 4);
        proc(c5, base + i + 5);
        proc(c6, base + i + 6);
        proc(c7, base + i + 7);
        if (__any(cnt >= DEPTH - 7)) {
            flush();
            lim = fminf(key[K_ - 1], bound);
        }
        if ((i & 56) == 56) {
            thr2d[w][lane] = key[K_ - 1];
            float m0 = fminf(thr2d[0][lane], thr2d[1][lane]);
            float m1 = fminf(thr2d[2][lane], thr2d[3][lane]);
            float m2 = fminf(thr2d[4][lane], thr2d[5][lane]);
            float m3 = fminf(thr2d[6][lane], thr2d[7][lane]);
            bound = fminf(fminf(m0, m1), fminf(m2, m3));
            lim = fminf(key[K_ - 1], bound);
        }
    }
    flush();

#pragma unroll
    for (int j = 0; j < K_; j++) bufp[j][t] = make_float2(key[j], __int_as_float(id[j]));

    int* op = idxOut + ((size_t)b * N_ + q) * K_;
    for (int step = 1; step < S_; step <<= 1) {
        bool active = (w & (2 * step - 1)) == 0;
        float md[K_];
        int   mi[K_];
        __syncthreads();
        if (active) {
            int pa = t, pb = t + step * 64;
            int ia = 0, ib = 0;
#pragma unroll
            for (int r = 0; r < K_; ++r) {
                float2 ea = bufp[ia][pa];
                float2 eb = bufp[ib][pb];
                bool sel = ea.x <= eb.x;
                md[r] = sel ? ea.x : eb.x;
                mi[r] = __float_as_int(sel ? ea.y : eb.y);
                ia += sel ? 1 : 0;
                ib += sel ? 0 : 1;
            }
        }
        __syncthreads();
        if (active) {
            if (step == S_ / 2) {
#pragma unroll
                for (int r = 0; r < K_; ++r) op[r] = mi[r];
            } else {
#pragma unroll
                for (int r = 0; r < K_; ++r) bufp[r][t] = make_float2(md[r], __int_as_float(mi[r]));
            }
        }
    }
}

// ---------------- device-scope grid barrier (persistent kernel) ----------------
__device__ __forceinline__ void gridbar(int* cnt, int target) {
    __syncthreads();
    if (threadIdx.x == 0) {
        __threadfence();
        atomicAdd(cnt, 1);
        while (__hip_atomic_load(cnt, __ATOMIC_RELAXED, __HIP_MEMORY_SCOPE_AGENT) < target)
            __builtin_amdgcn_s_sleep(2);
        __threadfence();
    }
    __syncthreads();
}

// ---------------- persistent fused tail v4: fp16 L2-resident gather, XCD-swizzled ----------------
// 512 blocks x 512 threads (2/CU, 16 waves/CU). 8 threads/row, 64 rows/block.
// XCD swizzle: vbid=(bid&7)*64+(bid>>3) -> each XCD serves ONE batch slice whose
// 4 MB fp16 feats table fits its private L2. Gather: 1 uint4 (8 halves) per
// neighbor per thread, 16 independent loads. Weights via wave-uniform s_load.
__global__ __launch_bounds__(512, 4) void fused_tail(
        const __half* __restrict__ fh, const int* __restrict__ idx,
        const float* __restrict__ W1, const float* __restrict__ b1,
        const float* __restrict__ g1, const float* __restrict__ be1,
        const float* __restrict__ Wa, const float* __restrict__ ba,
        const float* __restrict__ ga, const float* __restrict__ bea,
        const float* __restrict__ W2, const float* __restrict__ b2,
        const float* __restrict__ g2, const float* __restrict__ be2,
        float* __restrict__ out,
        float* __restrict__ part1, float* __restrict__ part2, float* __restrict__ part3,
        int* __restrict__ barcnt) {
    __shared__ float buf[ROWS][65];    // 16.6 KB, odd stride -> conflict-free
    __shared__ float red[256];
    __shared__ float scs[128], shs[128];

    int t = threadIdx.x;
    int rl = t & 63;                                   // row within block
    int h2 = __builtin_amdgcn_readfirstlane(t >> 6);   // eighth id (0..7), wave-uniform
    int vbid = ((blockIdx.x & 7) << 6) + (blockIdx.x >> 3);   // XCD-contiguous mapping
    int row = vbid * ROWS + rl;
    int bb = row >> 13;

    const __half* fb = fh + ((size_t)bb << 13) * 64;
    const int* ip = idx + (size_t)row * K_;

    // ---- gather + mean: this thread's 8 channels [h2*8, h2*8+8)
    {
        float xh[8];
#pragma unroll
        for (int j = 0; j < 8; j++) xh[j] = 0.0f;
#pragma unroll
        for (int j = 0; j < K_; j++) {
            uint4 a = *(const uint4*)(fb + (((size_t)ip[j]) << 6) + h2 * 8);
            __half2* hp = (__half2*)&a;
#pragma unroll
            for (int p = 0; p < 4; p++) {
                float2 f = __half22float2(hp[p]);
                xh[2 * p] += f.x;
                xh[2 * p + 1] += f.y;
            }
        }
#pragma unroll
        for (int j = 0; j < 8; j++) buf[rl][h2 * 8 + j] = xh[j] * (1.0f / 16.0f);
    }
    __syncthreads();

    // ---- mm1: 8 outputs; x read in 16-chunks from LDS; weights via s_load
    float acc[8];
#pragma unroll
    for (int j = 0; j < 8; j++) acc[j] = b1[h2 * 8 + j];
#pragma unroll 1
    for (int c0 = 0; c0 < 64; c0 += 16) {
        float xr[16];
#pragma unroll
        for (int j = 0; j < 16; j++) xr[j] = buf[rl][c0 + j];
#pragma unroll
        for (int cc = 0; cc < 16; cc++) {
            float xv = xr[cc];
            const float* wr = W1 + (c0 + cc) * 64 + h2 * 8;
#pragma unroll
            for (int j = 0; j < 8; j++) acc[j] = fmaf(xv, wr[j], acc[j]);
        }
    }

    // ---- stage y1, stats partials
    __syncthreads();
#pragma unroll
    for (int j = 0; j < 8; j++) buf[rl][h2 * 8 + j] = acc[j];
    __syncthreads();
    if (t < 128) {
        int c = t & 63;
        float s = 0.0f;
        if (t < 64) { for (int r = 0; r < ROWS; ++r) s += buf[r][c]; }
        else        { for (int r = 0; r < ROWS; ++r) { float v = buf[r][c]; s = fmaf(v, v, s); } }
        part1[blockIdx.x * 128 + t] = s;
    }
    gridbar(barcnt, NBLK);

    if (t < 128) {
        float s = 0.0f;
#pragma unroll 8
        for (int g = 0; g < NBLK; ++g) s += part1[g * 128 + t];
        red[t] = s;
    }
    __syncthreads();
    if (t < 64) {
        float mean = red[t] * (1.0f / BN_);
        float var = red[t + 64] * (1.0f / BN_) - mean * mean;
        float rstd = rsqrtf(var + EPS_);
        float scl = rstd * g1[t];
        scs[t] = scl;
        shs[t] = be1[t] - mean * scl;
    }
    __syncthreads();

    // ---- x1 = relu(bn1(y1)); keep own slice; stage full x1
    float x1s[8];
#pragma unroll
    for (int j = 0; j < 8; j++) {
        x1s[j] = fmaxf(0.0f, fmaf(acc[j], scs[h2 * 8 + j], shs[h2 * 8 + j]));
        buf[rl][h2 * 8 + j] = x1s[j];
    }
    __syncthreads();

    // ---- mm2: y2 = x1 @ Wa + ba
#pragma unroll
    for (int j = 0; j < 8; j++) acc[j] = ba[h2 * 8 + j];
#pragma unroll 1
    for (int c0 = 0; c0 < 64; c0 += 16) {
        float xr[16];
#pragma unroll
        for (int j = 0; j < 16; j++) xr[j] = buf[rl][c0 + j];
#pragma unroll
        for (int cc = 0; cc < 16; cc++) {
            float xv = xr[cc];
            const float* wr = Wa + (c0 + cc) * 64 + h2 * 8;
#pragma unroll
            for (int j = 0; j < 8; j++) acc[j] = fmaf(xv, wr[j], acc[j]);
        }
    }

    // ---- stage y2, stats partials
    __syncthreads();
#pragma unroll
    for (int j = 0; j < 8; j++) buf[rl][h2 * 8 + j] = acc[j];
    __syncthreads();
    if (t < 128) {
        int c = t & 63;
        float s = 0.0f;
        if (t < 64) { for (int r = 0; r < ROWS; ++r) s += buf[r][c]; }
        else        { for (int r = 0; r < ROWS; ++r) { float v = buf[r][c]; s = fmaf(v, v, s); } }
        part2[blockIdx.x * 128 + t] = s;
    }
    gridbar(barcnt, 2 * NBLK);

    if (t < 128) {
        float s = 0.0f;
#pragma unroll 8
        for (int g = 0; g < NBLK; ++g) s += part2[g * 128 + t];
        red[t] = s;
    }
    __syncthreads();
    if (t < 64) {
        float mean = red[t] * (1.0f / BN_);
        float var = red[t + 64] * (1.0f / BN_) - mean * mean;
        float rstd = rsqrtf(var + EPS_);
        float scl = rstd * ga[t];
        scs[t] = scl;
        shs[t] = bea[t] - mean * scl;
    }
    __syncthreads();

    // ---- fx = x1 * (1 + sigmoid(relu(bn2(y2)))); stage full fx
#pragma unroll
    for (int j = 0; j < 8; j++) {
        float tv = fmaxf(0.0f, fmaf(acc[j], scs[h2 * 8 + j], shs[h2 * 8 + j]));
        float a = 1.0f / (1.0f + __expf(-tv));
        buf[rl][h2 * 8 + j] = x1s[j] * (1.0f + a);
    }
    __syncthreads();

    // ---- mm3: 16 outputs per thread [h2*16, h2*16+16)
    float acc16[16];
#pragma unroll
    for (int j = 0; j < 16; j++) acc16[j] = b2[h2 * 16 + j];
#pragma unroll 1
    for (int c0 = 0; c0 < 64; c0 += 16) {
        float xr[16];
#pragma unroll
        for (int j = 0; j < 16; j++) xr[j] = buf[rl][c0 + j];
#pragma unroll
        for (int cc = 0; cc < 16; cc++) {
            float xv = xr[cc];
            const float* wr = W2 + (c0 + cc) * 128 + h2 * 16;
#pragma unroll
            for (int j = 0; j < 16; j++) acc16[j] = fmaf(xv, wr[j], acc16[j]);
        }
    }

    // ---- y3 stats: round 0 (ch 0-63 from h2<4), round 1 (ch 64-127 from h2>=4)
    __syncthreads();
    if (h2 < 4) {
#pragma unroll
        for (int j = 0; j < 16; j++) buf[rl][h2 * 16 + j] = acc16[j];
    }
    __syncthreads();
    if (t < 128) {
        int c = t & 63;
        float s = 0.0f;
        if (t < 64) { for (int r = 0; r < ROWS; ++r) s += buf[r][c]; }
        else        { for (int r = 0; r < ROWS; ++r) { float v = buf[r][c]; s = fmaf(v, v, s); } }
        part3[blockIdx.x * 256 + t] = s;
    }
    __syncthreads();
    if (h2 >= 4) {
#pragma unroll
        for (int j = 0; j < 16; j++) buf[rl][(h2 - 4) * 16 + j] = acc16[j];
    }
    __syncthreads();
    if (t < 128) {
        int c = t & 63;
        float s = 0.0f;
        if (t < 64) { for (int r = 0; r < ROWS; ++r) s += buf[r][c]; }
        else        { for (int r = 0; r < ROWS; ++r) { float v = buf[r][c]; s = fmaf(v, v, s); } }
        part3[blockIdx.x * 256 + 128 + t] = s;
    }
    gridbar(barcnt, 3 * NBLK);

    if (t < 256) {
        float s = 0.0f;
#pragma unroll 8
        for (int g = 0; g < NBLK; ++g) s += part3[g * 256 + t];
        red[t] = s;
    }
    __syncthreads();
    if (t < 128) {
        int c = t;
        int si = (c < 64) ? c : (c + 64);     // sum slot; sumsq at si+64
        float mean = red[si] * (1.0f / BN_);
        float var = red[si + 64] * (1.0f / BN_) - mean * mean;
        float rstd = rsqrtf(var + EPS_);
        float scl = rstd * g2[c];
        scs[c] = scl;
        shs[c] = be2[c] - mean * scl;
    }
    __syncthreads();

    // ---- final: normalize in registers, single output write
    float4* op = (float4*)(out + (size_t)row * 128 + h2 * 16);
#pragma unroll
    for (int f = 0; f < 4; f++) {
        int c0 = h2 * 16 + 4 * f;
        float4 v;
        v.x = fmaxf(0.0f, fmaf(acc16[4 * f],     scs[c0],     shs[c0]));
        v.y = fmaxf(0.0f, fmaf(acc16[4 * f + 1], scs[c0 + 1], shs[c0 + 1]));
        v.z = fmaxf(0.0f, fmaf(acc16[4 * f + 2], scs[c0 + 2], shs[c0 + 2]));
        v.w = fmaxf(0.0f, fmaf(acc16[4 * f + 3], scs[c0 + 3], shs[c0 + 3]));
        op[f] = v;
    }
}

extern "C" void kernel_launch(void* const* d_in, const int* in_sizes, int n_in,
                              void* d_out, int out_size, void* d_ws, size_t ws_size,
                              hipStream_t stream) {
    const float* coords = (const float*)d_in[0];
    const float* feats  = (const float*)d_in[1];
    const float* W1  = (const float*)d_in[3];
    const float* b1  = (const float*)d_in[4];
    const float* g1  = (const float*)d_in[5];
    const float* be1 = (const float*)d_in[6];
    const float* Wa  = (const float*)d_in[7];
    const float* ba  = (const float*)d_in[8];
    const float* ga  = (const float*)d_in[9];
    const float* bea = (const float*)d_in[10];
    const float* W2  = (const float*)d_in[11];
    const float* b2  = (const float*)d_in[12];
    const float* g2  = (const float*)d_in[13];
    const float* be2 = (const float*)d_in[14];

    float* ws = (float*)d_ws;
    float4* coords4 = (float4*)ws;                         // 131072 floats
    int*    idxbuf  = (int*)(ws + 131072);                 // BN_*16 ints
    __half* fh      = (__half*)(ws + 131072 + 524288);     // BN_*64 halves = 1,048,576 float slots
    float*  part1 = ws + 131072 + 524288 + 1048576;        // NBLK*128
    float*  part2 = part1 + NBLK * 128;                    // NBLK*128
    float*  part3 = part2 + NBLK * 128;                    // NBLK*256
    int*    barcnt = (int*)(part3 + NBLK * 256);
    float*  y3 = (float*)d_out;

    hipMemsetAsync(barcnt, 0, 64, stream);
    pack_coords<<<(BN_ + 255) / 256, 256, 0, stream>>>(coords, coords4);
    feats2h<<<BN_ * 64 / 8 / 256, 256, 0, stream>>>(feats, fh);
    knn_kernel<<<B_ * (N_ / QPB), TPB, 0, stream>>>(coords4, idxbuf);

    fused_tail<<<NBLK, 512, 0, stream>>>(fh, idxbuf,
                                         W1, b1, g1, be1,
                                         Wa, ba, ga, bea,
                                         W2, b2, g2, be2,
                                         y3, part1, part2, part3, barcnt);
}

// Round 10
// 287.155 us; speedup vs baseline: 1.7118x; 1.4890x over previous
//
#include <hip/hip_runtime.h>
#include <hip/hip_bf16.h>
#include <hip/hip_fp16.h>
#include <math.h>

#define B_ 4
#define N_ 8192
#define K_ 16
#define BN_ (B_ * N_)
#define EPS_ 1e-5f

#define S_ 8              // candidate splits = waves per block (knn)
#define TPB (S_ * 64)     // 512 threads (knn)
#define QPB 64            // queries per block (knn)
#define MCAND (N_ / S_)   // candidates per wave (knn)
#define DEPTH 16          // deferred-insert buffer depth per lane (knn)

#define NBLK 512          // tail grid (A/B/C)
#define ROWS 64           // rows per tail block (8 threads/row)

// ---------------- pack coords (B*N,3) -> float4 ----------------
__global__ __launch_bounds__(256) void pack_coords(const float* __restrict__ coords,
                                                   float4* __restrict__ out) {
    int i = blockIdx.x * 256 + threadIdx.x;
    if (i >= BN_) return;
    out[i] = make_float4(coords[3 * i], coords[3 * i + 1], coords[3 * i + 2], 0.0f);
}

// ---------------- feats fp32 -> fp16 ----------------
__global__ __launch_bounds__(256) void feats2h(const float* __restrict__ in,
                                               __half* __restrict__ outh) {
    int i = blockIdx.x * 256 + threadIdx.x;       // one thread per 8 elements
    const float4* p = (const float4*)(in + (size_t)i * 8);
    float4 a = p[0], b = p[1];
    __half2 h0; h0.x = __float2half_rn(a.x); h0.y = __float2half_rn(a.y);
    __half2 h1; h1.x = __float2half_rn(a.z); h1.y = __float2half_rn(a.w);
    __half2 h2; h2.x = __float2half_rn(b.x); h2.y = __float2half_rn(b.y);
    __half2 h3; h3.x = __float2half_rn(b.z); h3.y = __float2half_rn(b.w);
    uint4 o;
    o.x = *(unsigned*)&h0; o.y = *(unsigned*)&h1; o.z = *(unsigned*)&h2; o.w = *(unsigned*)&h3;
    ((uint4*)outh)[i] = o;
}

// ---------------- exact 16-NN (unchanged) ----------------
__global__ __launch_bounds__(512) void knn_kernel(const float4* __restrict__ coords4,
                                                  int* __restrict__ idxOut) {
    __shared__ float2 bufp[DEPTH][TPB];
    __shared__ float thr2d[S_][64];

    const int bpb = N_ / QPB;
    int b = blockIdx.x / bpb;
    int qbase = (blockIdx.x % bpb) * QPB;
    int t = threadIdx.x;
    int lane = t & 63;
    int w = __builtin_amdgcn_readfirstlane(t >> 6);
    int q = qbase + lane;

    thr2d[t >> 6][lane] = 3.4e38f;
    __syncthreads();

    const float4* cb = coords4 + (size_t)b * N_;
    float4 qc = cb[q];
    float qx = qc.x, qy = qc.y, qz = qc.z;

    float key[K_];
    int   id[K_];
#pragma unroll
    for (int j = 0; j < K_; j++) { key[j] = 3.4e38f; id[j] = -1; }

    int cnt = 0;
    float bound = 3.4e38f;
    float lim = 3.4e38f;

    auto flush = [&]() {
        for (int j = 0; j < cnt; ++j) {
            float2 e = bufp[j][t];
            float d2 = e.x;
            int   m  = __float_as_int(e.y);
            if (d2 < key[K_ - 1]) {
#pragma unroll
                for (int jj = K_ - 1; jj > 0; --jj) {
                    bool up = d2 < key[jj - 1];
                    float ik = fminf(d2, key[jj]);
                    int   ii = (d2 < key[jj]) ? m : id[jj];
                    key[jj] = up ? key[jj - 1] : ik;
                    id[jj]  = up ? id[jj - 1]  : ii;
                }
                if (d2 < key[0]) { key[0] = d2; id[0] = m; }
            }
        }
        cnt = 0;
    };

    auto proc = [&](float4 c, int m) {
        float dx = qx - c.x, dy = qy - c.y, dz = qz - c.z;
        float d2 = dx * dx;
        d2 = fmaf(dy, dy, d2);
        d2 = fmaf(dz, dz, d2);
        if (d2 < lim) {
            bufp[cnt][t] = make_float2(d2, __int_as_float(m));
            cnt++;
        }
    };

    const int base = w * MCAND;
    for (int i = 0; i < MCAND; i += 8) {
        float4 c0 = cb[base + i + 0];
        float4 c1 = cb[base + i + 1];
        float4 c2 = cb[base + i + 2];
        float4 c3 = cb[base + i + 3];
        float4 c4 = cb[base + i + 4];
        float4 c5 = cb[base + i + 5];
        float4 c6 = cb[base + i + 6];
        float4 c7 = cb[base + i + 7];
        proc(c0, base + i + 0);
        proc(c1, base + i + 1);
        proc(c2, base + i + 2);
        proc(c3, base + i + 3);
        proc(c4, base + i + 4);
        proc(c5, base + i + 5);
        proc(c6, base + i + 6);
        proc(c7, base + i + 7);
        if (__any(cnt >= DEPTH - 7)) {
            flush();
            lim = fminf(key[K_ - 1], bound);
        }
        if ((i & 56) == 56) {
            thr2d[w][lane] = key[K_ - 1];
            float m0 = fminf(thr2d[0][lane], thr2d[1][lane]);
            float m1 = fminf(thr2d[2][lane], thr2d[3][lane]);
            float m2 = fminf(thr2d[4][lane], thr2d[5][lane]);
            float m3 = fminf(thr2d[6][lane], thr2d[7][lane]);
            bound = fminf(fminf(m0, m1), fminf(m2, m3));
            lim = fminf(key[K_ - 1], bound);
        }
    }
    flush();

#pragma unroll
    for (int j = 0; j < K_; j++) bufp[j][t] = make_float2(key[j], __int_as_float(id[j]));

    int* op = idxOut + ((size_t)b * N_ + q) * K_;
    for (int step = 1; step < S_; step <<= 1) {
        bool active = (w & (2 * step - 1)) == 0;
        float md[K_];
        int   mi[K_];
        __syncthreads();
        if (active) {
            int pa = t, pb = t + step * 64;
            int ia = 0, ib = 0;
#pragma unroll
            for (int r = 0; r < K_; ++r) {
                float2 ea = bufp[ia][pa];
                float2 eb = bufp[ib][pb];
                bool sel = ea.x <= eb.x;
                md[r] = sel ? ea.x : eb.x;
                mi[r] = __float_as_int(sel ? ea.y : eb.y);
                ia += sel ? 1 : 0;
                ib += sel ? 0 : 1;
            }
        }
        __syncthreads();
        if (active) {
            if (step == S_ / 2) {
#pragma unroll
                for (int r = 0; r < K_; ++r) op[r] = mi[r];
            } else {
#pragma unroll
                for (int r = 0; r < K_; ++r) bufp[r][t] = make_float2(md[r], __int_as_float(mi[r]));
            }
        }
    }
}

// ---------------- A: fp16 gather (XCD-swizzled) + mean + mm1 + part1 ----------------
__global__ __launch_bounds__(512) void g1_kernel(const __half* __restrict__ fh,
                                                 const int* __restrict__ idx,
                                                 const float* __restrict__ W1,
                                                 const float* __restrict__ b1,
                                                 float* __restrict__ Y1,
                                                 float* __restrict__ part1) {
    __shared__ float buf[ROWS][65];
    int t = threadIdx.x;
    int rl = t & 63;
    int h2 = __builtin_amdgcn_readfirstlane(t >> 6);
    int vbid = ((blockIdx.x & 7) << 6) + (blockIdx.x >> 3);   // XCD-contiguous
    int row = vbid * ROWS + rl;
    int bb = row >> 13;

    const __half* fb = fh + ((size_t)bb << 13) * 64;
    const int* ip = idx + (size_t)row * K_;

    float xh[8];
#pragma unroll
    for (int j = 0; j < 8; j++) xh[j] = 0.0f;
#pragma unroll
    for (int j = 0; j < K_; j++) {
        uint4 a = *(const uint4*)(fb + (((size_t)ip[j]) << 6) + h2 * 8);
        __half2* hp = (__half2*)&a;
#pragma unroll
        for (int p = 0; p < 4; p++) {
            float2 f = __half22float2(hp[p]);
            xh[2 * p] += f.x;
            xh[2 * p + 1] += f.y;
        }
    }
#pragma unroll
    for (int j = 0; j < 8; j++) buf[rl][h2 * 8 + j] = xh[j] * (1.0f / 16.0f);
    __syncthreads();

    float acc[8];
#pragma unroll
    for (int j = 0; j < 8; j++) acc[j] = b1[h2 * 8 + j];
#pragma unroll 1
    for (int c0 = 0; c0 < 64; c0 += 16) {
        float xr[16];
#pragma unroll
        for (int j = 0; j < 16; j++) xr[j] = buf[rl][c0 + j];
#pragma unroll
        for (int cc = 0; cc < 16; cc++) {
            float xv = xr[cc];
            const float* wr = W1 + (c0 + cc) * 64 + h2 * 8;
#pragma unroll
            for (int j = 0; j < 8; j++) acc[j] = fmaf(xv, wr[j], acc[j]);
        }
    }
    // write y1 (global), then reuse buf for stats
    float2* yp = (float2*)(Y1 + (size_t)row * 64 + h2 * 8);
#pragma unroll
    for (int f = 0; f < 4; f++) yp[f] = make_float2(acc[2 * f], acc[2 * f + 1]);
    __syncthreads();
#pragma unroll
    for (int j = 0; j < 8; j++) buf[rl][h2 * 8 + j] = acc[j];
    __syncthreads();
    if (t < 128) {
        int c = t & 63;
        float s = 0.0f;
        if (t < 64) { for (int r = 0; r < ROWS; ++r) s += buf[r][c]; }
        else        { for (int r = 0; r < ROWS; ++r) { float v = buf[r][c]; s = fmaf(v, v, s); } }
        part1[blockIdx.x * 128 + t] = s;
    }
}

// ---------------- shared: reduce [NBLK][128] partials -> scs/shs (64 ch) ----------------
__device__ __forceinline__ void reduce_stats64(const float* __restrict__ part,
                                               const float* __restrict__ gma,
                                               const float* __restrict__ bta,
                                               float* red4, float* scs, float* shs) {
    int t = threadIdx.x;
    {
        int c = t & 127;
        int q = t >> 7;                        // 4-way split over g
        float s = 0.0f;
#pragma unroll 8
        for (int g = q * 128; g < q * 128 + 128; ++g) s += part[(size_t)g * 128 + c];
        red4[t] = s;
    }
    __syncthreads();
    if (t < 128) red4[t] = red4[t] + red4[t + 128] + red4[t + 256] + red4[t + 384];
    __syncthreads();
    if (t < 64) {
        float mean = red4[t] * (1.0f / BN_);
        float var = red4[t + 64] * (1.0f / BN_) - mean * mean;
        float rstd = rsqrtf(var + EPS_);
        float scl = rstd * gma[t];
        scs[t] = scl;
        shs[t] = bta[t] - mean * scl;
    }
    __syncthreads();
}

// ---------------- B: stats1 + bn1/relu -> x1, mm2 -> y2 + part2 ----------------
__global__ __launch_bounds__(512) void m2_kernel(const float* __restrict__ Y1,
                                                 const float* __restrict__ Wa,
                                                 const float* __restrict__ ba,
                                                 const float* __restrict__ g1,
                                                 const float* __restrict__ be1,
                                                 const float* __restrict__ part1,
                                                 float* __restrict__ X1,
                                                 float* __restrict__ Y2,
                                                 float* __restrict__ part2) {
    __shared__ float buf[ROWS][65];
    __shared__ float red4[512];
    __shared__ float scs[64], shs[64];
    int t = threadIdx.x;
    int rl = t & 63;
    int h2 = __builtin_amdgcn_readfirstlane(t >> 6);
    int row = blockIdx.x * ROWS + rl;

    reduce_stats64(part1, g1, be1, red4, scs, shs);

    // x1 slice = relu(bn1(y1 slice)); write x1, stage
    const float2* y1p = (const float2*)(Y1 + (size_t)row * 64 + h2 * 8);
    float2* x1p = (float2*)(X1 + (size_t)row * 64 + h2 * 8);
#pragma unroll
    for (int f = 0; f < 4; f++) {
        float2 v = y1p[f];
        int c0 = h2 * 8 + 2 * f;
        float a = fmaxf(0.0f, fmaf(v.x, scs[c0], shs[c0]));
        float b = fmaxf(0.0f, fmaf(v.y, scs[c0 + 1], shs[c0 + 1]));
        x1p[f] = make_float2(a, b);
        buf[rl][c0] = a;
        buf[rl][c0 + 1] = b;
    }
    __syncthreads();

    float acc[8];
#pragma unroll
    for (int j = 0; j < 8; j++) acc[j] = ba[h2 * 8 + j];
#pragma unroll 1
    for (int c0 = 0; c0 < 64; c0 += 16) {
        float xr[16];
#pragma unroll
        for (int j = 0; j < 16; j++) xr[j] = buf[rl][c0 + j];
#pragma unroll
        for (int cc = 0; cc < 16; cc++) {
            float xv = xr[cc];
            const float* wr = Wa + (c0 + cc) * 64 + h2 * 8;
#pragma unroll
            for (int j = 0; j < 8; j++) acc[j] = fmaf(xv, wr[j], acc[j]);
        }
    }
    float2* y2p = (float2*)(Y2 + (size_t)row * 64 + h2 * 8);
#pragma unroll
    for (int f = 0; f < 4; f++) y2p[f] = make_float2(acc[2 * f], acc[2 * f + 1]);
    __syncthreads();
#pragma unroll
    for (int j = 0; j < 8; j++) buf[rl][h2 * 8 + j] = acc[j];
    __syncthreads();
    if (t < 128) {
        int c = t & 63;
        float s = 0.0f;
        if (t < 64) { for (int r = 0; r < ROWS; ++r) s += buf[r][c]; }
        else        { for (int r = 0; r < ROWS; ++r) { float v = buf[r][c]; s = fmaf(v, v, s); } }
        part2[blockIdx.x * 128 + t] = s;
    }
}

// ---------------- C: stats2 + attn + fused, mm3 -> y3(unnorm) + part3 ----------------
__global__ __launch_bounds__(512) void m3_kernel(const float* __restrict__ Y2,
                                                 const float* __restrict__ X1,
                                                 const float* __restrict__ W2,
                                                 const float* __restrict__ b2,
                                                 const float* __restrict__ ga,
                                                 const float* __restrict__ bea,
                                                 const float* __restrict__ part2,
                                                 float* __restrict__ Y3,
                                                 float* __restrict__ part3) {
    __shared__ float buf[ROWS][65];
    __shared__ float red4[512];
    __shared__ float scs[64], shs[64];
    int t = threadIdx.x;
    int rl = t & 63;
    int h2 = __builtin_amdgcn_readfirstlane(t >> 6);
    int row = blockIdx.x * ROWS + rl;

    reduce_stats64(part2, ga, bea, red4, scs, shs);

    const float2* y2p = (const float2*)(Y2 + (size_t)row * 64 + h2 * 8);
    const float2* x1p = (const float2*)(X1 + (size_t)row * 64 + h2 * 8);
#pragma unroll
    for (int f = 0; f < 4; f++) {
        float2 v = y2p[f];
        float2 u = x1p[f];
        int c0 = h2 * 8 + 2 * f;
        float t0 = fmaxf(0.0f, fmaf(v.x, scs[c0], shs[c0]));
        float t1 = fmaxf(0.0f, fmaf(v.y, scs[c0 + 1], shs[c0 + 1]));
        float a0 = 1.0f / (1.0f + __expf(-t0));
        float a1 = 1.0f / (1.0f + __expf(-t1));
        buf[rl][c0] = u.x * (1.0f + a0);
        buf[rl][c0 + 1] = u.y * (1.0f + a1);
    }
    __syncthreads();

    float acc16[16];
#pragma unroll
    for (int j = 0; j < 16; j++) acc16[j] = b2[h2 * 16 + j];
#pragma unroll 1
    for (int c0 = 0; c0 < 64; c0 += 16) {
        float xr[16];
#pragma unroll
        for (int j = 0; j < 16; j++) xr[j] = buf[rl][c0 + j];
#pragma unroll
        for (int cc = 0; cc < 16; cc++) {
            float xv = xr[cc];
            const float* wr = W2 + (c0 + cc) * 128 + h2 * 16;
#pragma unroll
            for (int j = 0; j < 16; j++) acc16[j] = fmaf(xv, wr[j], acc16[j]);
        }
    }
    float4* yp = (float4*)(Y3 + (size_t)row * 128 + h2 * 16);
#pragma unroll
    for (int f = 0; f < 4; f++)
        yp[f] = make_float4(acc16[4 * f], acc16[4 * f + 1], acc16[4 * f + 2], acc16[4 * f + 3]);

    // y3 stats in two LDS rounds
    __syncthreads();
    if (h2 < 4) {
#pragma unroll
        for (int j = 0; j < 16; j++) buf[rl][h2 * 16 + j] = acc16[j];
    }
    __syncthreads();
    if (t < 128) {
        int c = t & 63;
        float s = 0.0f;
        if (t < 64) { for (int r = 0; r < ROWS; ++r) s += buf[r][c]; }
        else        { for (int r = 0; r < ROWS; ++r) { float v = buf[r][c]; s = fmaf(v, v, s); } }
        part3[blockIdx.x * 256 + t] = s;
    }
    __syncthreads();
    if (h2 >= 4) {
#pragma unroll
        for (int j = 0; j < 16; j++) buf[rl][(h2 - 4) * 16 + j] = acc16[j];
    }
    __syncthreads();
    if (t < 128) {
        int c = t & 63;
        float s = 0.0f;
        if (t < 64) { for (int r = 0; r < ROWS; ++r) s += buf[r][c]; }
        else        { for (int r = 0; r < ROWS; ++r) { float v = buf[r][c]; s = fmaf(v, v, s); } }
        part3[blockIdx.x * 256 + 128 + t] = s;
    }
}

// ---------------- D: stats3 + final normalize in place ----------------
__global__ __launch_bounds__(256) void bnf_kernel(float* __restrict__ Y3,
                                                  const float* __restrict__ g2,
                                                  const float* __restrict__ be2,
                                                  const float* __restrict__ part3) {
    __shared__ float red[256];
    __shared__ float scs[128], shs[128];
    int t = threadIdx.x;
    {
        float s = 0.0f;
#pragma unroll 8
        for (int g = 0; g < NBLK; ++g) s += part3[(size_t)g * 256 + t];
        red[t] = s;
    }
    __syncthreads();
    if (t < 128) {
        int si = (t < 64) ? t : (t + 64);     // sum slot; sumsq at si+64
        float mean = red[si] * (1.0f / BN_);
        float var = red[si + 64] * (1.0f / BN_) - mean * mean;
        float rstd = rsqrtf(var + EPS_);
        float scl = rstd * g2[t];
        scs[t] = scl;
        shs[t] = be2[t] - mean * scl;
    }
    __syncthreads();
    const int total = BN_ * 128 / 4;
    float4* p = (float4*)Y3;
    for (int i = blockIdx.x * 256 + t; i < total; i += 256 * 256) {
        float4 v = p[i];
        int c0 = (i * 4) & 127;
        v.x = fmaxf(0.0f, fmaf(v.x, scs[c0],     shs[c0]));
        v.y = fmaxf(0.0f, fmaf(v.y, scs[c0 + 1], shs[c0 + 1]));
        v.z = fmaxf(0.0f, fmaf(v.z, scs[c0 + 2], shs[c0 + 2]));
        v.w = fmaxf(0.0f, fmaf(v.w, scs[c0 + 3], shs[c0 + 3]));
        p[i] = v;
    }
}

extern "C" void kernel_launch(void* const* d_in, const int* in_sizes, int n_in,
                              void* d_out, int out_size, void* d_ws, size_t ws_size,
                              hipStream_t stream) {
    const float* coords = (const float*)d_in[0];
    const float* feats  = (const float*)d_in[1];
    const float* W1  = (const float*)d_in[3];
    const float* b1  = (const float*)d_in[4];
    const float* g1  = (const float*)d_in[5];
    const float* be1 = (const float*)d_in[6];
    const float* Wa  = (const float*)d_in[7];
    const float* ba  = (const float*)d_in[8];
    const float* ga  = (const float*)d_in[9];
    const float* bea = (const float*)d_in[10];
    const float* W2  = (const float*)d_in[11];
    const float* b2  = (const float*)d_in[12];
    const float* g2  = (const float*)d_in[13];
    const float* be2 = (const float*)d_in[14];

    float* ws = (float*)d_ws;
    float4* coords4 = (float4*)ws;                         // 131072 f
    int*    idxbuf  = (int*)(ws + 131072);                 // 524288 slots
    __half* fh      = (__half*)(ws + 131072 + 524288);     // 1048576 f-slots
    float*  y1 = ws + 131072 + 524288 + 1048576;           // BN_*64
    float*  x1 = y1 + (size_t)BN_ * 64;
    float*  y2 = x1 + (size_t)BN_ * 64;
    float*  part1 = y2 + (size_t)BN_ * 64;                 // NBLK*128
    float*  part2 = part1 + NBLK * 128;
    float*  part3 = part2 + NBLK * 128;                    // NBLK*256
    float*  y3 = (float*)d_out;

    pack_coords<<<(BN_ + 255) / 256, 256, 0, stream>>>(coords, coords4);
    feats2h<<<BN_ * 64 / 8 / 256, 256, 0, stream>>>(feats, fh);
    knn_kernel<<<B_ * (N_ / QPB), TPB, 0, stream>>>(coords4, idxbuf);

    g1_kernel<<<NBLK, 512, 0, stream>>>(fh, idxbuf, W1, b1, y1, part1);
    m2_kernel<<<NBLK, 512, 0, stream>>>(y1, Wa, ba, g1, be1, part1, x1, y2, part2);
    m3_kernel<<<NBLK, 512, 0, stream>>>(y2, x1, W2, b2, ga, bea, part2, y3, part3);
    bnf_kernel<<<256, 256, 0, stream>>>(y3, g2, be2, part3);
}